// Round 6
// baseline (97.354 us; speedup 1.0000x reference)
//
#include <hip/hip_runtime.h>
#include <hip/hip_fp16.h>

// DistMult forward scoring: score[e] = sum_d h[src,d] * fwd_rel[et,d] * h[dst,d]
// E=640000, D=128, fp32 in/out.
//
// R5: fp16 gather path (R4) + doubled memory-level parallelism.
// - prologue converts h, fwd_rel to fp16 in d_ws (absmax 0.25 << 1.28 thr)
// - fp16 h table (2.56 MB) is L2-resident per XCD; no dim-split needed
// - fp16 fwd_rel (125 KB) staged in LDS (ds_read_b128, off the L2 path)
// - 16-lane team gathers full 256 B rows at 16 B/lane (coalesced)
// - 8 edges/team/iter: 16 outstanding row gathers to hide L2 latency
//   (occupancy is pinned at 1 block/CU by the 128 KB LDS; per-wave MLP is
//   the only latency-hiding lever)

typedef unsigned short u16;

constexpr int EMB_DIM  = 128;
constexpr int MAX_RELS = 500;
constexpr int BLOCKS   = 256;    // 1 per CU
constexpr int THREADS  = 1024;   // 64 teams of 16 lanes
constexpr int EPT      = 8;      // edges per team per iteration

// ---- prologue: fp32 -> fp16 pack, 8 floats per thread ----
__global__ __launch_bounds__(256) void convert_fp16_kernel(
    const float* __restrict__ a, u16* __restrict__ a16, int n_a8,
    const float* __restrict__ b, u16* __restrict__ b16, int n_b8)
{
    const int total = n_a8 + n_b8;
    for (int i = blockIdx.x * blockDim.x + threadIdx.x; i < total;
         i += gridDim.x * blockDim.x) {
        const float* s; u16* d; int j;
        if (i < n_a8) { s = a; d = a16; j = i; }
        else          { s = b; d = b16; j = i - n_a8; }
        float4 lo = reinterpret_cast<const float4*>(s)[j * 2];
        float4 hi = reinterpret_cast<const float4*>(s)[j * 2 + 1];
        u16 u0 = __half_as_ushort(__float2half(lo.x));
        u16 u1 = __half_as_ushort(__float2half(lo.y));
        u16 u2 = __half_as_ushort(__float2half(lo.z));
        u16 u3 = __half_as_ushort(__float2half(lo.w));
        u16 u4 = __half_as_ushort(__float2half(hi.x));
        u16 u5 = __half_as_ushort(__float2half(hi.y));
        u16 u6 = __half_as_ushort(__float2half(hi.z));
        u16 u7 = __half_as_ushort(__float2half(hi.w));
        uint4 v;
        v.x = (unsigned)u0 | ((unsigned)u1 << 16);
        v.y = (unsigned)u2 | ((unsigned)u3 << 16);
        v.z = (unsigned)u4 | ((unsigned)u5 << 16);
        v.w = (unsigned)u6 | ((unsigned)u7 << 16);
        reinterpret_cast<uint4*>(d)[j] = v;
    }
}

__device__ __forceinline__ float dot8(uint4 A, uint4 B, uint4 C) {
    const __half2* a2 = reinterpret_cast<const __half2*>(&A);
    const __half2* b2 = reinterpret_cast<const __half2*>(&B);
    const __half2* c2 = reinterpret_cast<const __half2*>(&C);
    float acc = 0.f;
    #pragma unroll
    for (int k = 0; k < 4; ++k) {
        float2 fa = __half22float2(a2[k]);
        float2 fb = __half22float2(b2[k]);
        float2 fc = __half22float2(c2[k]);
        acc += fa.x * fb.x * fc.x + fa.y * fb.y * fc.y;
    }
    return acc;
}

__global__ __launch_bounds__(THREADS) void distmult_fp16_kernel(
    const u16* __restrict__ h16,     // [n_nodes][128] fp16
    const int* __restrict__ src,
    const int* __restrict__ dst,
    const int* __restrict__ etype,
    const u16* __restrict__ w16,     // [n_rels][128] fp16
    float*     __restrict__ out,
    int n_edges, int n_rels)
{
    __shared__ u16 w_lds[MAX_RELS * EMB_DIM];   // 125 KB

    // stage fwd_rel fp16 into LDS (linear, coalesced uint4)
    {
        const int slots = n_rels * (EMB_DIM / 8);     // uint4 slots
        for (int s = threadIdx.x; s < slots; s += THREADS)
            reinterpret_cast<uint4*>(w_lds)[s] =
                reinterpret_cast<const uint4*>(w16)[s];
    }
    __syncthreads();

    const int team = threadIdx.x >> 4;   // 64 teams
    const int lane = threadIdx.x & 15;

    const uint4* hp = reinterpret_cast<const uint4*>(h16) + lane;  // +16/row
    const uint4* wl = reinterpret_cast<const uint4*>(w_lds) + lane;

    const int stride = BLOCKS * (THREADS / 16) * EPT;   // 131072 edges/pass

    for (int e0 = (blockIdx.x * (THREADS / 16) + team) * EPT; e0 < n_edges;
         e0 += stride) {
        if (e0 + EPT - 1 < n_edges) {
            // 6 int4 index loads covering 8 edges
            const int4 sA = *reinterpret_cast<const int4*>(src   + e0);
            const int4 sB = *reinterpret_cast<const int4*>(src   + e0 + 4);
            const int4 dA = *reinterpret_cast<const int4*>(dst   + e0);
            const int4 dB = *reinterpret_cast<const int4*>(dst   + e0 + 4);
            const int4 tA = *reinterpret_cast<const int4*>(etype + e0);
            const int4 tB = *reinterpret_cast<const int4*>(etype + e0 + 4);

            const int si[EPT] = {sA.x, sA.y, sA.z, sA.w, sB.x, sB.y, sB.z, sB.w};
            const int di[EPT] = {dA.x, dA.y, dA.z, dA.w, dB.x, dB.y, dB.z, dB.w};
            const int ti[EPT] = {tA.x, tA.y, tA.z, tA.w, tB.x, tB.y, tB.z, tB.w};

            // 16 outstanding L2 row-gathers + 8 LDS reads
            uint4 A[EPT], C[EPT], B[EPT];
            #pragma unroll
            for (int k = 0; k < EPT; ++k) A[k] = hp[(size_t)si[k] * 16];
            #pragma unroll
            for (int k = 0; k < EPT; ++k) C[k] = hp[(size_t)di[k] * 16];
            #pragma unroll
            for (int k = 0; k < EPT; ++k) B[k] = wl[(size_t)ti[k] * 16];

            float acc[EPT];
            #pragma unroll
            for (int k = 0; k < EPT; ++k) acc[k] = dot8(A[k], B[k], C[k]);

            #pragma unroll
            for (int off = 8; off > 0; off >>= 1)
                #pragma unroll
                for (int k = 0; k < EPT; ++k)
                    acc[k] += __shfl_down(acc[k], off, 16);

            if (lane == 0) {
                *reinterpret_cast<float4*>(out + e0) =
                    make_float4(acc[0], acc[1], acc[2], acc[3]);
                *reinterpret_cast<float4*>(out + e0 + 4) =
                    make_float4(acc[4], acc[5], acc[6], acc[7]);
            }
        } else {
            for (int k = 0; k < EPT; ++k) {
                const int e = e0 + k;
                if (e >= n_edges) break;
                uint4 a = hp[(size_t)src[e] * 16];
                uint4 c = hp[(size_t)dst[e] * 16];
                uint4 b = wl[(size_t)etype[e] * 16];
                float acc = dot8(a, b, c);
                #pragma unroll
                for (int off = 8; off > 0; off >>= 1)
                    acc += __shfl_down(acc, off, 16);
                if (lane == 0) out[e] = acc;
            }
        }
    }
}

// fallback: fp32 direct (R0-style) if ws too small or n_rels > MAX_RELS
__global__ __launch_bounds__(256) void distmult_score_kernel(
    const float* __restrict__ h,
    const int*   __restrict__ src,
    const int*   __restrict__ dst,
    const int*   __restrict__ etype,
    const float* __restrict__ fwd_rel,
    float*       __restrict__ out,
    int n_edges)
{
    const int tid  = blockIdx.x * blockDim.x + threadIdx.x;
    const int lane = threadIdx.x & 63;
    const int half = lane >> 5;
    const int sub  = lane & 31;
    const int edge = (tid >> 6) * 2 + half;
    if (edge >= n_edges) return;

    const int s = src[edge];
    const int d = dst[edge];
    const int e = etype[edge];

    const float4 a = reinterpret_cast<const float4*>(h       + (size_t)s * EMB_DIM)[sub];
    const float4 b = reinterpret_cast<const float4*>(fwd_rel + (size_t)e * EMB_DIM)[sub];
    const float4 c = reinterpret_cast<const float4*>(h       + (size_t)d * EMB_DIM)[sub];

    float acc = a.x*b.x*c.x + a.y*b.y*c.y + a.z*b.z*c.z + a.w*b.w*c.w;
    #pragma unroll
    for (int off = 16; off > 0; off >>= 1)
        acc += __shfl_down(acc, off, 32);
    if (sub == 0) out[edge] = acc;
}

extern "C" void kernel_launch(void* const* d_in, const int* in_sizes, int n_in,
                              void* d_out, int out_size, void* d_ws, size_t ws_size,
                              hipStream_t stream) {
    const float* h       = (const float*)d_in[0];
    const int*   src     = (const int*)d_in[1];
    const int*   dst     = (const int*)d_in[2];
    const int*   etype   = (const int*)d_in[3];
    const float* fwd_rel = (const float*)d_in[4];
    float* out = (float*)d_out;

    const int n_edges = in_sizes[1];
    const int n_h     = in_sizes[0];              // n_nodes*128
    const int n_w     = in_sizes[4];              // n_rels*128
    const int n_rels  = n_w / EMB_DIM;
    const size_t need = (size_t)(n_h + n_w) * sizeof(u16);

    if (ws_size >= need && n_rels <= MAX_RELS &&
        (n_h % 8) == 0 && (n_w % 8) == 0) {
        u16* h16 = (u16*)d_ws;
        u16* w16 = h16 + n_h;

        const int n_a8 = n_h / 8, n_b8 = n_w / 8;
        const int cgrid = (n_a8 + n_b8 + 255) / 256;
        convert_fp16_kernel<<<cgrid, 256, 0, stream>>>(
            h, h16, n_a8, fwd_rel, w16, n_b8);

        distmult_fp16_kernel<<<BLOCKS, THREADS, 0, stream>>>(
            h16, src, dst, etype, w16, out, n_edges, n_rels);
    } else {
        const int grid = (n_edges + 7) / 8;
        distmult_score_kernel<<<grid, 256, 0, stream>>>(
            h, src, dst, etype, fwd_rel, out, n_edges);
    }
}

// Round 7
// 93.427 us; speedup vs baseline: 1.0420x; 1.0420x over previous
//
#include <hip/hip_runtime.h>
#include <hip/hip_fp16.h>

// DistMult forward scoring: score[e] = sum_d h[src,d] * fwd_rel[et,d] * h[dst,d]
// E=640000, D=128, fp32 in/out.
//
// R6 = R4 restored (best measured config). Evidence across R2-R5:
// - limiter is L2 random-gather channel throughput; measured efficiency
//   ~66-70% of the 8 XCD x 16 ch x 64 B x 2.4 GHz ideal, reproduced by two
//   unrelated kernel structures (fp32 dim-split and fp16 whole-row).
// - fp16 halves bytes/edge vs fp32 (absmax 0.25 << 1.28 thr; bf16 would be
//   ~2.0 -> fail, fp8 far worse). h16 table (2.56 MB) is L2-resident per XCD,
//   no dim-split / no partials needed.
// - fwd_rel fp16 (125 KB) staged in LDS: off the L2 path entirely.
// - EPT=4 (8 outstanding row-gathers/team) is the measured optimum; EPT=8
//   regressed (queueing at the channel ceiling, no latency left to hide).
// - occupancy pinned at 1 block/CU by 125 KB LDS -- intentional trade.

typedef unsigned short u16;

constexpr int EMB_DIM  = 128;
constexpr int MAX_RELS = 500;
constexpr int BLOCKS   = 256;    // 1 per CU
constexpr int THREADS  = 1024;   // 64 teams of 16 lanes

// ---- prologue: fp32 -> fp16 pack, 8 floats per thread ----
__global__ __launch_bounds__(256) void convert_fp16_kernel(
    const float* __restrict__ a, u16* __restrict__ a16, int n_a8,
    const float* __restrict__ b, u16* __restrict__ b16, int n_b8)
{
    const int total = n_a8 + n_b8;
    for (int i = blockIdx.x * blockDim.x + threadIdx.x; i < total;
         i += gridDim.x * blockDim.x) {
        const float* s; u16* d; int j;
        if (i < n_a8) { s = a; d = a16; j = i; }
        else          { s = b; d = b16; j = i - n_a8; }
        float4 lo = reinterpret_cast<const float4*>(s)[j * 2];
        float4 hi = reinterpret_cast<const float4*>(s)[j * 2 + 1];
        u16 u0 = __half_as_ushort(__float2half(lo.x));
        u16 u1 = __half_as_ushort(__float2half(lo.y));
        u16 u2 = __half_as_ushort(__float2half(lo.z));
        u16 u3 = __half_as_ushort(__float2half(lo.w));
        u16 u4 = __half_as_ushort(__float2half(hi.x));
        u16 u5 = __half_as_ushort(__float2half(hi.y));
        u16 u6 = __half_as_ushort(__float2half(hi.z));
        u16 u7 = __half_as_ushort(__float2half(hi.w));
        uint4 v;
        v.x = (unsigned)u0 | ((unsigned)u1 << 16);
        v.y = (unsigned)u2 | ((unsigned)u3 << 16);
        v.z = (unsigned)u4 | ((unsigned)u5 << 16);
        v.w = (unsigned)u6 | ((unsigned)u7 << 16);
        reinterpret_cast<uint4*>(d)[j] = v;
    }
}

__device__ __forceinline__ float dot8(uint4 A, uint4 B, uint4 C) {
    const __half2* a2 = reinterpret_cast<const __half2*>(&A);
    const __half2* b2 = reinterpret_cast<const __half2*>(&B);
    const __half2* c2 = reinterpret_cast<const __half2*>(&C);
    float acc = 0.f;
    #pragma unroll
    for (int k = 0; k < 4; ++k) {
        float2 fa = __half22float2(a2[k]);
        float2 fb = __half22float2(b2[k]);
        float2 fc = __half22float2(c2[k]);
        acc += fa.x * fb.x * fc.x + fa.y * fb.y * fc.y;
    }
    return acc;
}

__global__ __launch_bounds__(THREADS) void distmult_fp16_kernel(
    const u16* __restrict__ h16,     // [n_nodes][128] fp16
    const int* __restrict__ src,
    const int* __restrict__ dst,
    const int* __restrict__ etype,
    const u16* __restrict__ w16,     // [n_rels][128] fp16
    float*     __restrict__ out,
    int n_edges, int n_rels)
{
    __shared__ u16 w_lds[MAX_RELS * EMB_DIM];   // 125 KB

    // stage fwd_rel fp16 into LDS (linear, coalesced uint4)
    {
        const int slots = n_rels * (EMB_DIM / 8);     // uint4 slots
        for (int s = threadIdx.x; s < slots; s += THREADS)
            reinterpret_cast<uint4*>(w_lds)[s] =
                reinterpret_cast<const uint4*>(w16)[s];
    }
    __syncthreads();

    const int team = threadIdx.x >> 4;   // 64 teams
    const int lane = threadIdx.x & 15;

    const uint4* hp = reinterpret_cast<const uint4*>(h16) + lane;  // +16/row
    const uint4* wl = reinterpret_cast<const uint4*>(w_lds) + lane;

    const int stride = BLOCKS * (THREADS / 16) * 4;   // 65536 edges/pass

    for (int e0 = (blockIdx.x * (THREADS / 16) + team) * 4; e0 < n_edges;
         e0 += stride) {
        if (e0 + 3 < n_edges) {
            const int4 s4 = *reinterpret_cast<const int4*>(src   + e0);
            const int4 d4 = *reinterpret_cast<const int4*>(dst   + e0);
            const int4 t4 = *reinterpret_cast<const int4*>(etype + e0);

            // 8 L2 gathers: full 256 B fp16 rows, 16 B/lane
            uint4 a0 = hp[(size_t)s4.x * 16];
            uint4 a1 = hp[(size_t)s4.y * 16];
            uint4 a2 = hp[(size_t)s4.z * 16];
            uint4 a3 = hp[(size_t)s4.w * 16];
            uint4 c0 = hp[(size_t)d4.x * 16];
            uint4 c1 = hp[(size_t)d4.y * 16];
            uint4 c2 = hp[(size_t)d4.z * 16];
            uint4 c3 = hp[(size_t)d4.w * 16];
            // 4 LDS reads for w
            uint4 b0 = wl[(size_t)t4.x * 16];
            uint4 b1 = wl[(size_t)t4.y * 16];
            uint4 b2 = wl[(size_t)t4.z * 16];
            uint4 b3 = wl[(size_t)t4.w * 16];

            float acc0 = dot8(a0, b0, c0);
            float acc1 = dot8(a1, b1, c1);
            float acc2 = dot8(a2, b2, c2);
            float acc3 = dot8(a3, b3, c3);

            #pragma unroll
            for (int off = 8; off > 0; off >>= 1) {
                acc0 += __shfl_down(acc0, off, 16);
                acc1 += __shfl_down(acc1, off, 16);
                acc2 += __shfl_down(acc2, off, 16);
                acc3 += __shfl_down(acc3, off, 16);
            }
            if (lane == 0)
                *reinterpret_cast<float4*>(out + e0) =
                    make_float4(acc0, acc1, acc2, acc3);
        } else {
            for (int k = 0; k < 4; ++k) {
                const int e = e0 + k;
                if (e >= n_edges) break;
                uint4 a = hp[(size_t)src[e] * 16];
                uint4 c = hp[(size_t)dst[e] * 16];
                uint4 b = wl[(size_t)etype[e] * 16];
                float acc = dot8(a, b, c);
                #pragma unroll
                for (int off = 8; off > 0; off >>= 1)
                    acc += __shfl_down(acc, off, 16);
                if (lane == 0) out[e] = acc;
            }
        }
    }
}

// fallback: fp32 direct (R0-style) if ws too small or n_rels > MAX_RELS
__global__ __launch_bounds__(256) void distmult_score_kernel(
    const float* __restrict__ h,
    const int*   __restrict__ src,
    const int*   __restrict__ dst,
    const int*   __restrict__ etype,
    const float* __restrict__ fwd_rel,
    float*       __restrict__ out,
    int n_edges)
{
    const int tid  = blockIdx.x * blockDim.x + threadIdx.x;
    const int lane = threadIdx.x & 63;
    const int half = lane >> 5;
    const int sub  = lane & 31;
    const int edge = (tid >> 6) * 2 + half;
    if (edge >= n_edges) return;

    const int s = src[edge];
    const int d = dst[edge];
    const int e = etype[edge];

    const float4 a = reinterpret_cast<const float4*>(h       + (size_t)s * EMB_DIM)[sub];
    const float4 b = reinterpret_cast<const float4*>(fwd_rel + (size_t)e * EMB_DIM)[sub];
    const float4 c = reinterpret_cast<const float4*>(h       + (size_t)d * EMB_DIM)[sub];

    float acc = a.x*b.x*c.x + a.y*b.y*c.y + a.z*b.z*c.z + a.w*b.w*c.w;
    #pragma unroll
    for (int off = 16; off > 0; off >>= 1)
        acc += __shfl_down(acc, off, 32);
    if (sub == 0) out[edge] = acc;
}

extern "C" void kernel_launch(void* const* d_in, const int* in_sizes, int n_in,
                              void* d_out, int out_size, void* d_ws, size_t ws_size,
                              hipStream_t stream) {
    const float* h       = (const float*)d_in[0];
    const int*   src     = (const int*)d_in[1];
    const int*   dst     = (const int*)d_in[2];
    const int*   etype   = (const int*)d_in[3];
    const float* fwd_rel = (const float*)d_in[4];
    float* out = (float*)d_out;

    const int n_edges = in_sizes[1];
    const int n_h     = in_sizes[0];              // n_nodes*128
    const int n_w     = in_sizes[4];              // n_rels*128
    const int n_rels  = n_w / EMB_DIM;
    const size_t need = (size_t)(n_h + n_w) * sizeof(u16);

    if (ws_size >= need && n_rels <= MAX_RELS &&
        (n_h % 8) == 0 && (n_w % 8) == 0) {
        u16* h16 = (u16*)d_ws;
        u16* w16 = h16 + n_h;

        const int n_a8 = n_h / 8, n_b8 = n_w / 8;
        const int cgrid = (n_a8 + n_b8 + 255) / 256;
        convert_fp16_kernel<<<cgrid, 256, 0, stream>>>(
            h, h16, n_a8, fwd_rel, w16, n_b8);

        distmult_fp16_kernel<<<BLOCKS, THREADS, 0, stream>>>(
            h16, src, dst, etype, w16, out, n_edges, n_rels);
    } else {
        const int grid = (n_edges + 7) / 8;
        distmult_score_kernel<<<grid, 256, 0, stream>>>(
            h, src, dst, etype, fwd_rel, out, n_edges);
    }
}